// Round 2
// baseline (744.566 us; speedup 1.0000x reference)
//
#include <hip/hip_runtime.h>
#include <math.h>

// Problem constants (from reference)
#define BB 16
#define NN 4096
#define DD 256
#define CC 8
#define KK 512
#define SD 32
#define NTOK (BB * NN)            // 65536 tokens
#define IDS_N (NTOK * CC)         // 524288
#define QN (NTOK * DD)            // 16777216
#define OFF_Q   (IDS_N)           // 524288
#define OFF_ST  (IDS_N + QN)      // 17301504
#define OFF_SC  (IDS_N + 2 * QN)  // 34078720

// ws layout:
//   [0..8)                double mse_sum
//   [16..16+16384)        float hist[CC*KK]
//   [32768..32768+1MB)    double cb64[CC*KK*SD]
//   [then..+16384)        float csqf[CC*KK]
#define WS_HIST_OFF 16
#define WS_CB64_OFF 32768
#define WS_CSQ_OFF  (32768 + CC * KK * SD * 8)
#define WS_ZERO_BYTES (16 + CC * KK * 4)

// Up-convert codebooks to f64 and precompute ||c||^2 (f64 -> f32, i.e.
// correctly rounded — within <=1 ulp of numpy's own f32 pairwise sum).
__global__ __launch_bounds__(256) void vq_prep(
    const float* __restrict__ cbs,
    double* __restrict__ cb64,
    float* __restrict__ csqf)
{
    const int cell = blockIdx.x * 256 + threadIdx.x;   // 16 blocks -> 4096 cells
    const float* cp = cbs + (size_t)cell * SD;
    double* dp = cb64 + (size_t)cell * SD;
    double s = 0.0;
    #pragma unroll
    for (int j = 0; j < 8; ++j) {
        float4 v = ((const float4*)cp)[j];
        double a = (double)v.x, b = (double)v.y, c = (double)v.z, d = (double)v.w;
        dp[4 * j + 0] = a; dp[4 * j + 1] = b;
        dp[4 * j + 2] = c; dp[4 * j + 3] = d;
        s = fma(a, a, s); s = fma(b, b, s);
        s = fma(c, c, s); s = fma(d, d, s);
    }
    csqf[cell] = (float)s;
}

__global__ __launch_bounds__(256) void vq_main(
    const float* __restrict__ latents,
    const float* __restrict__ mask,
    const double* __restrict__ cb64,
    const float* __restrict__ csq_g,
    float* __restrict__ out,
    double* __restrict__ mse_sum,
    float* __restrict__ hist)
{
    __shared__ float csqf[KK];    // 2 KB
    __shared__ double red[256];   // 2 KB

    const int c = blockIdx.x & 7;
    const int tokBlk = blockIdx.x >> 3;
    const int tid = threadIdx.x;
    const int token = tokBlk * 256 + tid;

    // Stage this codebook's ||c||^2 (f32) into LDS
    csqf[tid]       = csq_g[c * KK + tid];
    csqf[tid + 256] = csq_g[c * KK + tid + 256];
    __syncthreads();

    // Load x (32 floats), keep f64 copy for exact dot products
    const float* xp = latents + (size_t)token * DD + c * SD;
    double xd[SD];
    double xs = 0.0;
    #pragma unroll
    for (int j = 0; j < 8; ++j) {
        float4 v = ((const float4*)xp)[j];
        xd[4 * j + 0] = (double)v.x;
        xd[4 * j + 1] = (double)v.y;
        xd[4 * j + 2] = (double)v.z;
        xd[4 * j + 3] = (double)v.w;
        xs = fma((double)v.x, (double)v.x, xs);
        xs = fma((double)v.y, (double)v.y, xs);
        xs = fma((double)v.z, (double)v.z, xs);
        xs = fma((double)v.w, (double)v.w, xs);
    }
    const float xsqf = (float)xs;

    // Argmin over K codes, replicating numpy's f32 arithmetic at the final
    // combine: dist = fl32( fl32(xsq + csq[k]) - fl32(2*dot) ). The sub-terms
    // (xsq, csq, dot) are f64-accurate then rounded once to f32. Strict <
    // keeps the first index on quantized ties (matches np.argmin).
    const double* __restrict__ cbase = cb64 + (size_t)c * KK * SD;  // wave-uniform
    float best = 1e30f;
    int bid = 0;
    for (int k = 0; k < KK; ++k) {
        const double* cw = cbase + (size_t)k * SD;   // uniform -> s_load stream
        double d0 = 0.0, d1 = 0.0, d2 = 0.0, d3 = 0.0;
        #pragma unroll
        for (int j = 0; j < 8; ++j) {
            d0 = fma(cw[4 * j + 0], xd[4 * j + 0], d0);
            d1 = fma(cw[4 * j + 1], xd[4 * j + 1], d1);
            d2 = fma(cw[4 * j + 2], xd[4 * j + 2], d2);
            d3 = fma(cw[4 * j + 3], xd[4 * j + 3], d3);
        }
        float dotf = (float)((d0 + d1) + (d2 + d3));
        float t1 = xsqf + csqf[k];
        float dist = t1 - 2.0f * dotf;   // 2*dotf exact -> contraction-safe
        if (dist < best) { best = dist; bid = k; }
    }

    out[(size_t)token * CC + c] = (float)bid;

    // quant / st_quantized (f32, elementwise as numpy) + MSE partial (f64)
    const double* qp = cbase + (size_t)bid * SD;
    float* oq  = out + OFF_Q  + (size_t)token * DD + c * SD;
    float* ost = out + OFF_ST + (size_t)token * DD + c * SD;
    double acc = 0.0;
    #pragma unroll
    for (int j = 0; j < 8; ++j) {
        float4 qv, sv;
        qv.x = (float)qp[4 * j + 0];
        qv.y = (float)qp[4 * j + 1];
        qv.z = (float)qp[4 * j + 2];
        qv.w = (float)qp[4 * j + 3];
        {
            float xf = (float)xd[4 * j + 0]; sv.x = xf + (qv.x - xf);
            double d = xd[4 * j + 0] - (double)qv.x; acc = fma(d, d, acc);
        }
        {
            float xf = (float)xd[4 * j + 1]; sv.y = xf + (qv.y - xf);
            double d = xd[4 * j + 1] - (double)qv.y; acc = fma(d, d, acc);
        }
        {
            float xf = (float)xd[4 * j + 2]; sv.z = xf + (qv.z - xf);
            double d = xd[4 * j + 2] - (double)qv.z; acc = fma(d, d, acc);
        }
        {
            float xf = (float)xd[4 * j + 3]; sv.w = xf + (qv.w - xf);
            double d = xd[4 * j + 3] - (double)qv.w; acc = fma(d, d, acc);
        }
        ((float4*)oq)[j]  = qv;
        ((float4*)ost)[j] = sv;
    }

    atomicAdd(&hist[c * KK + bid], mask[token]);

    red[tid] = acc;
    __syncthreads();
    for (int s = 128; s > 0; s >>= 1) {
        if (tid < s) red[tid] += red[tid + s];
        __syncthreads();
    }
    if (tid == 0) atomicAdd(mse_sum, red[0]);
}

__global__ __launch_bounds__(512) void vq_final(
    const float* __restrict__ mask,
    const float* __restrict__ hist,
    const double* __restrict__ mse_sum,
    float* __restrict__ out)
{
    __shared__ double redm[512];
    __shared__ double s_denom;
    __shared__ double ent[CC];

    const int tid = threadIdx.x;

    double m = 0.0;
    for (int i = tid; i < NTOK; i += 512) m += (double)mask[i];
    redm[tid] = m;
    __syncthreads();
    for (int s = 256; s > 0; s >>= 1) {
        if (tid < s) redm[tid] += redm[tid + s];
        __syncthreads();
    }
    if (tid == 0) {
        double d = redm[0];
        s_denom = d > 1.0 ? d : 1.0;
    }
    __syncthreads();
    const double denom = s_denom;

    const int w = tid >> 6;
    const int lane = tid & 63;
    double t = 0.0;
    for (int k = lane; k < KK; k += 64) {
        double p = (double)hist[w * KK + k] / denom;
        t += p * log(p + 1e-8);
    }
    #pragma unroll
    for (int off = 32; off > 0; off >>= 1) t += __shfl_down(t, off, 64);
    if (lane == 0) ent[w] = -t;
    __syncthreads();

    if (tid == 0) {
        double mean = mse_sum[0] / (double)QN;
        out[OFF_SC + 0] = (float)(0.25 * mean);  // commitment
        out[OFF_SC + 1] = (float)(1.0 * mean);   // codebook
        double perp = 0.0;
        for (int cc = 0; cc < CC; ++cc) perp += exp(ent[cc]);
        out[OFF_SC + 2] = (float)(perp / (double)CC);
    }
}

extern "C" void kernel_launch(void* const* d_in, const int* in_sizes, int n_in,
                              void* d_out, int out_size, void* d_ws, size_t ws_size,
                              hipStream_t stream) {
    const float* latents = (const float*)d_in[0];
    const float* mask    = (const float*)d_in[1];
    const float* cbs     = (const float*)d_in[2];
    float* out = (float*)d_out;

    double* mse  = (double*)d_ws;
    float*  hist = (float*)((char*)d_ws + WS_HIST_OFF);
    double* cb64 = (double*)((char*)d_ws + WS_CB64_OFF);
    float*  csqf = (float*)((char*)d_ws + WS_CSQ_OFF);

    hipMemsetAsync(d_ws, 0, WS_ZERO_BYTES, stream);

    vq_prep<<<dim3((CC * KK) / 256), dim3(256), 0, stream>>>(cbs, cb64, csqf);
    vq_main<<<dim3((NTOK / 256) * CC), dim3(256), 0, stream>>>(
        latents, mask, cb64, csqf, out, mse, hist);
    vq_final<<<dim3(1), dim3(512), 0, stream>>>(mask, hist, mse, out);
}

// Round 3
// 639.137 us; speedup vs baseline: 1.1650x; 1.1650x over previous
//
#include <hip/hip_runtime.h>
#include <math.h>

// Problem constants
#define BB 16
#define NN 4096
#define DD 256
#define CC 8
#define KK 512
#define SD 32
#define NTOK (BB * NN)            // 65536
#define IDS_N (NTOK * CC)         // 524288
#define QN (NTOK * DD)            // 16777216
#define OFF_Q   (IDS_N)
#define OFF_ST  (IDS_N + QN)
#define OFF_SC  (IDS_N + 2 * QN)

// Margin gate: f32-pass score error <= ~3e-8; np-vs-exact flip requires
// exact gap <= ~1.6e-5 (2 fp32 grid quanta at dist~32 + subterm wobble).
// GUARD = 4e-5 gives 2.5x safety; flags ~1% of pairs.
#define GUARD 4e-5f
#define CAP 65536

// ws layout
// 0:   double mse_sum
// 8:   double mask_sum
// 16:  unsigned flag_count (+pad)
// 32:  float hist[CC*KK]            (16384 B)
// 32+16384: float csqf[CC*KK]       (16384 B)
// 32+32768: unsigned list[CAP]      (262144 B)
#define WS_ZERO (32 + 16384)

// ---------------------------------------------------------------------------
// Prep: csq (f64-accurate -> f32, same fma order as the round-2 kernel that
// verified absmax 0), plus parallel mask-sum (removes vq_final's serial loop).
__global__ __launch_bounds__(256) void vq_prep(
    const float* __restrict__ cbs, const float* __restrict__ mask,
    float* __restrict__ csqf, double* __restrict__ mask_sum)
{
    __shared__ double red[256];
    const int tid = threadIdx.x;
    const int cell = blockIdx.x * 256 + tid;     // 16 blocks -> 4096 cells
    const float* cp = cbs + (size_t)cell * SD;
    double s = 0.0;
    #pragma unroll
    for (int j = 0; j < 8; ++j) {
        float4 v = ((const float4*)cp)[j];
        double a = (double)v.x, b = (double)v.y, c = (double)v.z, d = (double)v.w;
        s = fma(a, a, s); s = fma(b, b, s);
        s = fma(c, c, s); s = fma(d, d, s);
    }
    csqf[cell] = (float)s;

    double m = 0.0;
    for (int i = cell; i < NTOK; i += 4096) m += (double)mask[i];
    red[tid] = m;
    __syncthreads();
    for (int st = 128; st > 0; st >>= 1) {
        if (tid < st) red[tid] += red[tid + st];
        __syncthreads();
    }
    if (tid == 0) atomicAdd(mask_sum, red[0]);
}

// ---------------------------------------------------------------------------
// Fast pass: f32 scoring s = csq - 2*x.c (order-identical to dist), T=2
// tokens/thread. Codebook streamed via wave-uniform loads (scalar path).
// Pairs with top-2 margin < GUARD are deferred to the exact re-resolve.
__global__ __launch_bounds__(256) void vq_fast(
    const float* __restrict__ latents, const float* __restrict__ mask,
    const float* __restrict__ cbs, const float* __restrict__ csq_g,
    float* __restrict__ out, double* __restrict__ mse_sum,
    float* __restrict__ hist, unsigned* __restrict__ count,
    unsigned* __restrict__ list)
{
    __shared__ double red[256];
    const int c = blockIdx.x & 7;
    const int tokBlk = blockIdx.x >> 3;
    const int tid = threadIdx.x;
    const int token0 = tokBlk * 512 + tid;
    const int token1 = token0 + 256;

    const float* __restrict__ cbase = cbs + (size_t)c * KK * SD;   // uniform
    const float* __restrict__ csqc  = csq_g + c * KK;              // uniform

    float4 X0[8], X1[8];
    {
        const float4* xp0 = (const float4*)(latents + (size_t)token0 * DD + c * SD);
        const float4* xp1 = (const float4*)(latents + (size_t)token1 * DD + c * SD);
        #pragma unroll
        for (int j = 0; j < 8; ++j) { X0[j] = xp0[j]; X1[j] = xp1[j]; }
    }

    float best0 = 1e30f, sec0 = 1e30f; int bid0 = 0;
    float best1 = 1e30f, sec1 = 1e30f; int bid1 = 0;

    for (int k = 0; k < KK; ++k) {
        const float4* cw = (const float4*)(cbase + k * SD);  // uniform -> s_load
        const float cs = csqc[k];
        float a0 = 0.f, b0 = 0.f, a1 = 0.f, b1 = 0.f;
        #pragma unroll
        for (int j = 0; j < 8; ++j) {
            float4 v = cw[j];
            a0 = fmaf(v.x, X0[j].x, a0); a0 = fmaf(v.y, X0[j].y, a0);
            b0 = fmaf(v.z, X0[j].z, b0); b0 = fmaf(v.w, X0[j].w, b0);
            a1 = fmaf(v.x, X1[j].x, a1); a1 = fmaf(v.y, X1[j].y, a1);
            b1 = fmaf(v.z, X1[j].z, b1); b1 = fmaf(v.w, X1[j].w, b1);
        }
        const float s0 = fmaf(-2.f, a0 + b0, cs);
        const float s1 = fmaf(-2.f, a1 + b1, cs);
        // strict < keeps first index; sec tracks runner-up value
        bid0 = (s0 < best0) ? k : bid0;
        sec0 = fminf(sec0, fmaxf(s0, best0));
        best0 = fminf(best0, s0);
        bid1 = (s1 < best1) ? k : bid1;
        sec1 = fminf(sec1, fmaxf(s1, best1));
        best1 = fminf(best1, s1);
    }

    double accTot = 0.0;

    // ---- token0 epilogue ----
    {
        const bool flag = (sec0 - best0) < GUARD;
        out[(size_t)token0 * CC + c] = (float)bid0;
        const float4* qp = (const float4*)(cbase + bid0 * SD);
        float* oq  = out + OFF_Q  + (size_t)token0 * DD + c * SD;
        float* ost = out + OFF_ST + (size_t)token0 * DD + c * SD;
        double acc = 0.0;
        #pragma unroll
        for (int j = 0; j < 8; ++j) {
            float4 qv = qp[j], sv;
            sv.x = X0[j].x + (qv.x - X0[j].x);
            sv.y = X0[j].y + (qv.y - X0[j].y);
            sv.z = X0[j].z + (qv.z - X0[j].z);
            sv.w = X0[j].w + (qv.w - X0[j].w);
            double d;
            d = (double)X0[j].x - (double)qv.x; acc = fma(d, d, acc);
            d = (double)X0[j].y - (double)qv.y; acc = fma(d, d, acc);
            d = (double)X0[j].z - (double)qv.z; acc = fma(d, d, acc);
            d = (double)X0[j].w - (double)qv.w; acc = fma(d, d, acc);
            ((float4*)oq)[j]  = qv;
            ((float4*)ost)[j] = sv;
        }
        if (!flag) {
            atomicAdd(&hist[c * KK + bid0], mask[token0]);
            accTot += acc;
        } else {
            unsigned slot = atomicAdd(count, 1u);
            if (slot < CAP) list[slot] = ((unsigned)token0 << 3) | (unsigned)c;
        }
    }
    // ---- token1 epilogue ----
    {
        const bool flag = (sec1 - best1) < GUARD;
        out[(size_t)token1 * CC + c] = (float)bid1;
        const float4* qp = (const float4*)(cbase + bid1 * SD);
        float* oq  = out + OFF_Q  + (size_t)token1 * DD + c * SD;
        float* ost = out + OFF_ST + (size_t)token1 * DD + c * SD;
        double acc = 0.0;
        #pragma unroll
        for (int j = 0; j < 8; ++j) {
            float4 qv = qp[j], sv;
            sv.x = X1[j].x + (qv.x - X1[j].x);
            sv.y = X1[j].y + (qv.y - X1[j].y);
            sv.z = X1[j].z + (qv.z - X1[j].z);
            sv.w = X1[j].w + (qv.w - X1[j].w);
            double d;
            d = (double)X1[j].x - (double)qv.x; acc = fma(d, d, acc);
            d = (double)X1[j].y - (double)qv.y; acc = fma(d, d, acc);
            d = (double)X1[j].z - (double)qv.z; acc = fma(d, d, acc);
            d = (double)X1[j].w - (double)qv.w; acc = fma(d, d, acc);
            ((float4*)oq)[j]  = qv;
            ((float4*)ost)[j] = sv;
        }
        if (!flag) {
            atomicAdd(&hist[c * KK + bid1], mask[token1]);
            accTot += acc;
        } else {
            unsigned slot = atomicAdd(count, 1u);
            if (slot < CAP) list[slot] = ((unsigned)token1 << 3) | (unsigned)c;
        }
    }

    red[tid] = accTot;
    __syncthreads();
    for (int st = 128; st > 0; st >>= 1) {
        if (tid < st) red[tid] += red[tid + st];
        __syncthreads();
    }
    if (tid == 0) atomicAdd(mse_sum, red[0]);
}

// ---------------------------------------------------------------------------
// Exact re-resolve: one wave per flagged (token,c). Replicates the round-2
// arithmetic bit-for-bit (f64 subterms -> single f32 rounding, np first-index
// tie-break), then patches ids/quant/st if changed and adds hist/mse.
__global__ __launch_bounds__(256) void vq_resolve(
    const float* __restrict__ latents, const float* __restrict__ mask,
    const float* __restrict__ cbs, const float* __restrict__ csq_g,
    float* __restrict__ out, double* __restrict__ mse_sum,
    float* __restrict__ hist, const unsigned* __restrict__ count,
    const unsigned* __restrict__ list)
{
    unsigned n = *count; if (n > CAP) n = CAP;
    const int lane  = threadIdx.x & 63;
    const int wave  = (blockIdx.x << 2) | (threadIdx.x >> 6);
    const int nwav  = gridDim.x << 2;

    for (unsigned i = wave; i < n; i += nwav) {
        const unsigned e = list[i];
        const int token = (int)(e >> 3), c = (int)(e & 7u);
        const float* xp = latents + (size_t)token * DD + c * SD;

        // xsq: identical fma order to the verified round-2 kernel
        double xd[SD]; double xs = 0.0;
        #pragma unroll
        for (int j = 0; j < 8; ++j) {
            float4 v = ((const float4*)xp)[j];
            xd[4*j+0] = (double)v.x; xd[4*j+1] = (double)v.y;
            xd[4*j+2] = (double)v.z; xd[4*j+3] = (double)v.w;
            xs = fma((double)v.x, (double)v.x, xs);
            xs = fma((double)v.y, (double)v.y, xs);
            xs = fma((double)v.z, (double)v.z, xs);
            xs = fma((double)v.w, (double)v.w, xs);
        }
        const float xsqf = (float)xs;
        const float* cbase = cbs + (size_t)c * KK * SD;
        const float* csqc  = csq_g + c * KK;

        // lane handles k in [lane*8, lane*8+8) -> lane order == k order
        float best = 1e30f; int bk = lane * 8;
        for (int j = 0; j < 8; ++j) {
            const int k = lane * 8 + j;
            const float* cw = cbase + k * SD;
            double d0 = 0.0, d1 = 0.0, d2 = 0.0, d3 = 0.0;
            #pragma unroll
            for (int q = 0; q < 8; ++q) {
                d0 = fma((double)cw[4*q+0], xd[4*q+0], d0);
                d1 = fma((double)cw[4*q+1], xd[4*q+1], d1);
                d2 = fma((double)cw[4*q+2], xd[4*q+2], d2);
                d3 = fma((double)cw[4*q+3], xd[4*q+3], d3);
            }
            const float dotf = (float)((d0 + d1) + (d2 + d3));
            const float t1 = xsqf + csqc[k];
            const float dist = t1 - 2.0f * dotf;
            if (dist < best) { best = dist; bk = k; }
        }
        #pragma unroll
        for (int off = 32; off > 0; off >>= 1) {
            float od = __shfl_down(best, off, 64);
            int   ok = __shfl_down(bk,   off, 64);
            if (od < best || (od == best && ok < bk)) { best = od; bk = ok; }
        }
        bk = __shfl(bk, 0, 64);

        const int oldid = (int)out[(size_t)token * CC + c];
        if (bk != oldid) {
            if (lane == 0) out[(size_t)token * CC + c] = (float)bk;
            if (lane < SD) {
                float q = cbase[bk * SD + lane];
                float x = xp[lane];
                out[OFF_Q  + (size_t)token * DD + c * SD + lane] = q;
                out[OFF_ST + (size_t)token * DD + c * SD + lane] = x + (q - x);
            }
        }
        // deferred hist + mse contributions
        double dd = 0.0;
        if (lane < SD) {
            double q = (double)cbase[bk * SD + lane];
            double df = (double)xp[lane] - q;
            dd = df * df;
        }
        #pragma unroll
        for (int off = 32; off > 0; off >>= 1) dd += __shfl_down(dd, off, 64);
        if (lane == 0) {
            atomicAdd(mse_sum, dd);
            atomicAdd(&hist[c * KK + bk], mask[token]);
        }
    }
}

// ---------------------------------------------------------------------------
__global__ __launch_bounds__(512) void vq_final(
    const float* __restrict__ hist, const double* __restrict__ mse_sum,
    const double* __restrict__ mask_sum, float* __restrict__ out)
{
    __shared__ double ent[CC];
    const int tid = threadIdx.x;
    double denom = *mask_sum; if (denom < 1.0) denom = 1.0;

    const int w = tid >> 6;
    const int lane = tid & 63;
    double t = 0.0;
    for (int k = lane; k < KK; k += 64) {
        double p = (double)hist[w * KK + k] / denom;
        t += p * log(p + 1e-8);
    }
    #pragma unroll
    for (int off = 32; off > 0; off >>= 1) t += __shfl_down(t, off, 64);
    if (lane == 0) ent[w] = -t;
    __syncthreads();

    if (tid == 0) {
        double mean = mse_sum[0] / (double)QN;
        out[OFF_SC + 0] = (float)(0.25 * mean);
        out[OFF_SC + 1] = (float)(1.0 * mean);
        double perp = 0.0;
        for (int cc = 0; cc < CC; ++cc) perp += exp(ent[cc]);
        out[OFF_SC + 2] = (float)(perp / (double)CC);
    }
}

extern "C" void kernel_launch(void* const* d_in, const int* in_sizes, int n_in,
                              void* d_out, int out_size, void* d_ws, size_t ws_size,
                              hipStream_t stream) {
    const float* latents = (const float*)d_in[0];
    const float* mask    = (const float*)d_in[1];
    const float* cbs     = (const float*)d_in[2];
    float* out = (float*)d_out;

    double*   mse      = (double*)d_ws;
    double*   mask_sum = (double*)((char*)d_ws + 8);
    unsigned* count    = (unsigned*)((char*)d_ws + 16);
    float*    hist     = (float*)((char*)d_ws + 32);
    float*    csqf     = (float*)((char*)d_ws + 32 + 16384);
    unsigned* list     = (unsigned*)((char*)d_ws + 32 + 32768);

    hipMemsetAsync(d_ws, 0, WS_ZERO, stream);

    vq_prep<<<dim3(16), dim3(256), 0, stream>>>(cbs, mask, csqf, mask_sum);
    vq_fast<<<dim3((NTOK / 512) * CC), dim3(256), 0, stream>>>(
        latents, mask, cbs, csqf, out, mse, hist, count, list);
    vq_resolve<<<dim3(512), dim3(256), 0, stream>>>(
        latents, mask, cbs, csqf, out, mse, hist, count, list);
    vq_final<<<dim3(1), dim3(512), 0, stream>>>(hist, mse, mask_sum, out);
}